// Round 5
// baseline (352.940 us; speedup 1.0000x reference)
//
#include <hip/hip_runtime.h>
#include <math.h>

// Problem constants (from setup_inputs):
#define T_STEPS   4
#define NODE_NUM  10000
#define NUM_NODES 50000
#define E         256     // embedding dim
#define TWO_E     512
#define CC        128     // C
#define TWO_C     256
#define ROWS      16      // rows per block in the MLP kernel (R5: 32->16 for occupancy)

typedef short bf16x8 __attribute__((ext_vector_type(8)));       // 8 bf16 = 4 VGPRs
typedef float f32x4  __attribute__((ext_vector_type(4)));       // MFMA accumulator
typedef unsigned short u16x4 __attribute__((ext_vector_type(4)));

#define MFMA16(a, b, c) __builtin_amdgcn_mfma_f32_16x16x32_bf16((a), (b), (c), 0, 0, 0)

// bf16 weights, transposed [N][K], module-scope device global (d_ws stays all-table).
// layout (elements): w1t @0 (512x256), w2t @131072 (128x512),
//                    w1ut @196608 (256x128), w2ut @229376 (256x256)
static __device__ unsigned short g_wt[294912];

// tanh-form gelu: x * sigmoid(1.5957691(x + 0.044715 x^3)); |err| vs exact ~1e-3
__device__ __forceinline__ float gelu_fast(float x) {
    float x2 = x * x;
    float p  = __builtin_fmaf(x2, 0.044715f, 1.0f);
    float z  = 1.59576912160573f * x * p;
    float e  = __expf(-z);
    return x * (1.0f / (1.0f + e));
}

// fp32 -> bf16 round-to-nearest-even (finite inputs only)
__device__ __forceinline__ unsigned short f2bf(float f) {
    unsigned int u = __builtin_bit_cast(unsigned int, f);
    u += 0x7fffu + ((u >> 16) & 1u);
    return (unsigned short)(u >> 16);
}

// ---------------- weight prep: fp32 [K][N] -> bf16 [N][K] ----------------
__global__ void prep_weights(const float* __restrict__ W1d, const float* __restrict__ W2d,
                             const float* __restrict__ W1u, const float* __restrict__ W2u) {
    int i = blockIdx.x * 256 + threadIdx.x;       // 0 .. 131071
    if (i < 131072) {  // w1t: [512][256] <- W1d [256][512]
        int n = i >> 8, k = i & 255;
        g_wt[i] = f2bf(W1d[(size_t)k * TWO_E + n]);
    }
    if (i < 65536) {   // w2t: [128][512] <- W2d [512][128]
        int n = i >> 9, k = i & 511;
        g_wt[131072 + i] = f2bf(W2d[(size_t)k * CC + n]);
    }
    if (i < 32768) {   // w1ut: [256][128] <- W1u [128][256]
        int n = i >> 7, k = i & 127;
        g_wt[196608 + i] = f2bf(W1u[(size_t)k * TWO_C + n]);
    }
    if (i < 65536) {   // w2ut: [256][256] <- W2u [256][256]
        int n = i >> 8, k = i & 255;
        g_wt[229376 + i] = f2bf(W2u[(size_t)k * E + n]);
    }
}

// ---------------- zero active table rows (float4, 4 rows/block) ----------------
__global__ void zero_rows_kernel(float* __restrict__ table,
                                 const int* __restrict__ indices,
                                 int gr0, int t0) {
    int gr = gr0 + blockIdx.x * 4 + (threadIdx.x >> 6);
    int trel = gr / NODE_NUM - t0;
    int idx = indices[gr];
    int c = (threadIdx.x & 63) * 4;
    float4 z = make_float4(0.f, 0.f, 0.f, 0.f);
    *reinterpret_cast<float4*>(&table[((size_t)trel * NUM_NODES + idx) * E + c]) = z;
}

// ---------------- scatter-add (duplicates must sum -> atomics) ----------------
__global__ void scatter_kernel(float* __restrict__ table,
                               const float* __restrict__ x,
                               const int* __restrict__ indices,
                               int gr0, int t0) {
    int gr = gr0 + blockIdx.x;
    int trel = gr / NODE_NUM - t0;
    int idx = indices[gr];
    atomicAdd(&table[((size_t)trel * NUM_NODES + idx) * E + threadIdx.x],
              x[(size_t)gr * E + threadIdx.x]);
}

// ---------------- fused gather -> LN_d -> MLP_d -> LN_u -> MLP_u ----------------
// 16 rows/block, 256 threads (4 waves). ~25 KB LDS -> 6 blocks/CU (24 waves).
// LDS aliasing (bytes):
//   region1 [0, 8448):        Xs bf16[16][264] -> H2f fp32[16][132] -> G1 bf16[16][264]
//   region2 [8448, 25088):    H1 bf16[16][520] -> H2b bf16[16][136]
__global__ __launch_bounds__(256, 6)
void mlp_kernel(const float* __restrict__ table,
                const float* __restrict__ batched_x,
                const int* __restrict__ indices,
                const float* __restrict__ lnd_s, const float* __restrict__ lnd_b,
                const float* __restrict__ b1d, const float* __restrict__ b2d,
                const float* __restrict__ lnu_s, const float* __restrict__ lnu_b,
                const float* __restrict__ b1u, const float* __restrict__ b2u,
                float* __restrict__ out,
                int gr0, int t0, int grLim) {
    __shared__ __align__(16) unsigned char smem[25088];
    __shared__ size_t rbase[ROWS];
    __shared__ int    ridx[ROWS];

    unsigned short* Xs  = (unsigned short*)smem;            // [16][264]
    float*          H2f = (float*)smem;                     // [16][132]
    unsigned short* G1  = (unsigned short*)smem;            // [16][264]
    unsigned short* H1  = (unsigned short*)(smem + 8448);   // [16][520]
    unsigned short* H2b = (unsigned short*)(smem + 8448);   // [16][136]

    const unsigned short* w1t  = g_wt;
    const unsigned short* w2t  = g_wt + 131072;
    const unsigned short* w1ut = g_wt + 196608;
    const unsigned short* w2ut = g_wt + 229376;

    const int tid = threadIdx.x;
    const int w = tid >> 6, lane = tid & 63;
    const int l16 = lane & 15, quad = lane >> 4;
    const int grb = gr0 + blockIdx.x * ROWS;

    if (tid < ROWS) {
        int gr = grb + tid;
        if (gr >= grLim) gr = grLim - 1;     // clamped dup row; out-store guarded later
        int trel = gr / NODE_NUM - t0;
        int idx = indices[gr];
        rbase[tid] = ((size_t)trel * NUM_NODES + idx) * E;
        ridx[tid]  = idx;
    }
    __syncthreads();

    // ---- gather + LN_d fully in registers: one wave owns one row per iteration ----
    // it=0..3: wave w handles local row it*4+w; lane holds cols 4*lane..4*lane+3.
    {
        const int c = lane * 4;
        float4 sc4 = *reinterpret_cast<const float4*>(&lnd_s[c]);
        float4 bi4 = *reinterpret_cast<const float4*>(&lnd_b[c]);
        float4 xv[4];
        #pragma unroll
        for (int it = 0; it < 4; ++it) {
            int r = it * 4 + w;
            float4 tv = *reinterpret_cast<const float4*>(&table[rbase[r] + c]);
            float4 bv = *reinterpret_cast<const float4*>(&batched_x[(size_t)ridx[r] * E + c]);
            xv[it].x = tv.x + bv.x; xv[it].y = tv.y + bv.y;
            xv[it].z = tv.z + bv.z; xv[it].w = tv.w + bv.w;
        }
        #pragma unroll
        for (int it = 0; it < 4; ++it) {
            int r = it * 4 + w;
            float4 v = xv[it];
            float s  = (v.x + v.y) + (v.z + v.w);
            float sq = v.x * v.x + v.y * v.y + v.z * v.z + v.w * v.w;
            #pragma unroll
            for (int m = 1; m < 64; m <<= 1) {
                s  += __shfl_xor(s,  m);
                sq += __shfl_xor(sq, m);
            }
            float mu  = s * (1.0f / E);
            float var = sq * (1.0f / E) - mu * mu;
            float rs  = rsqrtf(var + 1e-5f);
            u16x4 o;
            o.x = f2bf((v.x - mu) * rs * sc4.x + bi4.x);
            o.y = f2bf((v.y - mu) * rs * sc4.y + bi4.y);
            o.z = f2bf((v.z - mu) * rs * sc4.z + bi4.z);
            o.w = f2bf((v.w - mu) * rs * sc4.w + bi4.w);
            *reinterpret_cast<u16x4*>(&Xs[r * 264 + c]) = o;
        }
    }
    __syncthreads();

    // ---- GEMM1: H1[16][512] = gelu(Xs @ W1d + b1d), K=256 ----
    {
        bf16x8 af[8];
        #pragma unroll
        for (int ks = 0; ks < 8; ++ks)
            af[ks] = *reinterpret_cast<const bf16x8*>(&Xs[l16 * 264 + quad * 8 + ks * 32]);
        #pragma unroll
        for (int nt_ = 0; nt_ < 8; ++nt_) {
            int n = (w * 8 + nt_) * 16 + l16;
            const unsigned short* bp = w1t + (size_t)n * 256 + quad * 8;
            f32x4 a0 = {0.f, 0.f, 0.f, 0.f};
            #pragma unroll
            for (int ks = 0; ks < 8; ++ks) {
                bf16x8 b = *reinterpret_cast<const bf16x8*>(bp + ks * 32);
                a0 = MFMA16(af[ks], b, a0);
            }
            float bias = b1d[n];
            #pragma unroll
            for (int reg = 0; reg < 4; ++reg) {
                int r = quad * 4 + reg;
                H1[r * 520 + n] = f2bf(gelu_fast(a0[reg] + bias));
            }
        }
    }
    __syncthreads();

    // ---- GEMM2: H2f[16][128] = H1 @ W2d + b2d (fp32 out), K=512 ----
    {
        f32x4 acc2[2];
        acc2[0] = (f32x4){0.f, 0.f, 0.f, 0.f};
        acc2[1] = (f32x4){0.f, 0.f, 0.f, 0.f};
        #pragma unroll
        for (int kh = 0; kh < 2; ++kh) {
            bf16x8 af2[8];
            #pragma unroll
            for (int ks = 0; ks < 8; ++ks)
                af2[ks] = *reinterpret_cast<const bf16x8*>(
                    &H1[l16 * 520 + kh * 256 + quad * 8 + ks * 32]);
            #pragma unroll
            for (int nt2 = 0; nt2 < 2; ++nt2) {
                int n = (w * 2 + nt2) * 16 + l16;
                const unsigned short* bp = w2t + (size_t)n * 512 + kh * 256 + quad * 8;
                #pragma unroll
                for (int ks = 0; ks < 8; ++ks) {
                    bf16x8 b = *reinterpret_cast<const bf16x8*>(bp + ks * 32);
                    acc2[nt2] = MFMA16(af2[ks], b, acc2[nt2]);
                }
            }
        }
        __syncthreads();   // H1 reads done before H2f overwrites region1? (H2f=region1, H1=region2: different regions; this barrier orders Xs-region reuse)
        #pragma unroll
        for (int nt2 = 0; nt2 < 2; ++nt2) {
            int n = (w * 2 + nt2) * 16 + l16;
            float bias = b2d[n];
            #pragma unroll
            for (int reg = 0; reg < 4; ++reg) {
                int r = quad * 4 + reg;
                H2f[r * 132 + n] = acc2[nt2][reg] + bias;
            }
        }
    }
    __syncthreads();

    // ---- LN_u (C=128): 16 lanes/row, 8 cols each; write bf16 H2b (aliases H1) ----
    {
        int row = tid >> 4;           // lanes 0-15 of each 16-group share a row
        float s = 0.f, sq = 0.f;
        float vals[8];
        #pragma unroll
        for (int k = 0; k < 8; ++k) {
            float v = H2f[row * 132 + k * 16 + l16];
            vals[k] = v; s += v; sq += v * v;
        }
        s  += __shfl_xor(s, 1);  s  += __shfl_xor(s, 2);
        s  += __shfl_xor(s, 4);  s  += __shfl_xor(s, 8);
        sq += __shfl_xor(sq, 1); sq += __shfl_xor(sq, 2);
        sq += __shfl_xor(sq, 4); sq += __shfl_xor(sq, 8);
        float mu  = s * (1.0f / CC);
        float var = sq * (1.0f / CC) - mu * mu;
        float rs  = rsqrtf(var + 1e-5f);
        #pragma unroll
        for (int k = 0; k < 8; ++k) {
            int c = k * 16 + l16;
            float v = (vals[k] - mu) * rs * lnu_s[c] + lnu_b[c];
            H2b[row * 136 + c] = f2bf(v);
        }
    }
    __syncthreads();

    // ---- GEMM3: G1[16][256] = gelu(H2b @ W1u + b1u), K=128; G1 aliases H2f ----
    {
        bf16x8 af3[4];
        #pragma unroll
        for (int ks = 0; ks < 4; ++ks)
            af3[ks] = *reinterpret_cast<const bf16x8*>(&H2b[l16 * 136 + quad * 8 + ks * 32]);
        #pragma unroll
        for (int nt_ = 0; nt_ < 4; ++nt_) {
            int n = (w * 4 + nt_) * 16 + l16;
            const unsigned short* bp = w1ut + (size_t)n * 128 + quad * 8;
            f32x4 a0 = {0.f, 0.f, 0.f, 0.f};
            #pragma unroll
            for (int ks = 0; ks < 4; ++ks) {
                bf16x8 b = *reinterpret_cast<const bf16x8*>(bp + ks * 32);
                a0 = MFMA16(af3[ks], b, a0);
            }
            // all H2f/region1 reads happened in LN_u before the barrier above GEMM3?
            // LN_u read H2f; barrier after LN_u ordered those reads before these writes.
            float bias = b1u[n];
            #pragma unroll
            for (int reg = 0; reg < 4; ++reg) {
                int r = quad * 4 + reg;
                G1[r * 264 + n] = f2bf(gelu_fast(a0[reg] + bias));
            }
        }
    }
    __syncthreads();

    // ---- GEMM4: out[16][256] = G1 @ W2u + b2u (fp32 global), K=256 ----
    {
        bf16x8 af4[8];
        #pragma unroll
        for (int ks = 0; ks < 8; ++ks)
            af4[ks] = *reinterpret_cast<const bf16x8*>(&G1[l16 * 264 + quad * 8 + ks * 32]);
        #pragma unroll
        for (int nt_ = 0; nt_ < 4; ++nt_) {
            int n = (w * 4 + nt_) * 16 + l16;
            const unsigned short* bp = w2ut + (size_t)n * 256 + quad * 8;
            f32x4 a0 = {0.f, 0.f, 0.f, 0.f};
            #pragma unroll
            for (int ks = 0; ks < 8; ++ks) {
                bf16x8 b = *reinterpret_cast<const bf16x8*>(bp + ks * 32);
                a0 = MFMA16(af4[ks], b, a0);
            }
            float bias = b2u[n];
            #pragma unroll
            for (int reg = 0; reg < 4; ++reg) {
                int r = quad * 4 + reg;
                int g0 = grb + r;
                if (g0 < grLim) out[(size_t)g0 * E + n] = a0[reg] + bias;
            }
        }
    }
}

extern "C" void kernel_launch(void* const* d_in, const int* in_sizes, int n_in,
                              void* d_out, int out_size, void* d_ws, size_t ws_size,
                              hipStream_t stream) {
    const float* x     = (const float*)d_in[0];
    const float* bx    = (const float*)d_in[1];
    const int*   idxp  = (const int*)  d_in[2];
    const float* lnd_s = (const float*)d_in[3];
    const float* lnd_b = (const float*)d_in[4];
    const float* W1d   = (const float*)d_in[5];
    const float* b1d   = (const float*)d_in[6];
    const float* W2d   = (const float*)d_in[7];
    const float* b2d   = (const float*)d_in[8];
    const float* lnu_s = (const float*)d_in[9];
    const float* lnu_b = (const float*)d_in[10];
    const float* W1u   = (const float*)d_in[11];
    const float* b1u   = (const float*)d_in[12];
    const float* W2u   = (const float*)d_in[13];
    const float* b2u   = (const float*)d_in[14];
    float* out = (float*)d_out;
    float* table = (float*)d_ws;     // full ws for table slices (weights in g_wt)

    const size_t slice_bytes = (size_t)NUM_NODES * E * sizeof(float);
    int tb = (int)(ws_size / slice_bytes);
    if (tb < 1) tb = 1;
    if (tb > T_STEPS) tb = T_STEPS;

    prep_weights<<<512, 256, 0, stream>>>(W1d, W2d, W1u, W2u);

    for (int t0 = 0; t0 < T_STEPS; t0 += tb) {
        int tcur = T_STEPS - t0 < tb ? T_STEPS - t0 : tb;
        int nrows = tcur * NODE_NUM;
        int gr0 = t0 * NODE_NUM;
        int grLim = gr0 + nrows;
        zero_rows_kernel<<<nrows / 4, 256, 0, stream>>>(table, idxp, gr0, t0);
        scatter_kernel  <<<nrows, E, 0, stream>>>(table, x, idxp, gr0, t0);
        mlp_kernel<<<(nrows + ROWS - 1) / ROWS, 256, 0, stream>>>(
            table, bx, idxp, lnd_s, lnd_b, b1d, b2d,
            lnu_s, lnu_b, b1u, b2u, out, gr0, t0, grLim);
    }
}